// Round 1
// baseline (649.141 us; speedup 1.0000x reference)
//
#include <hip/hip_runtime.h>

#define N_NODES    100000
#define N_EDGES    1600000
#define IN_F       64
#define OUT_F      40
#define N_CLUSTERS 10000

// ---------------------------------------------------------------- degree count
__global__ void deg_count_kernel(const int* __restrict__ rows, int* __restrict__ deg) {
    int e = blockIdx.x * 256 + threadIdx.x;
    if (e < N_EDGES) atomicAdd(&deg[rows[e]], 1);
}

// deg includes self-loop (+1); dinv = rsqrt(deg)
__global__ void dinv_kernel(const int* __restrict__ deg, float* __restrict__ dinv) {
    int i = blockIdx.x * 256 + threadIdx.x;
    if (i < N_NODES) dinv[i] = rsqrtf((float)(deg[i] + 1));
}

// ---------------------------------------------------------------- scan (exclusive)
__global__ void scan1_kernel(const int* __restrict__ in, int* __restrict__ out,
                             int* __restrict__ partials, int n) {
    __shared__ int s[256];
    int t = threadIdx.x;
    int i = blockIdx.x * 256 + t;
    int v = (i < n) ? in[i] : 0;
    s[t] = v;
    __syncthreads();
    for (int off = 1; off < 256; off <<= 1) {
        int add = (t >= off) ? s[t - off] : 0;
        __syncthreads();
        s[t] += add;
        __syncthreads();
    }
    if (i < n) out[i] = s[t] - v;           // exclusive
    if (t == 255) partials[blockIdx.x] = s[255];
}

__global__ void scan2_kernel(int* __restrict__ p, int nb) {
    __shared__ int s[512];
    int t = threadIdx.x;
    int v = (t < nb) ? p[t] : 0;
    s[t] = v;
    __syncthreads();
    for (int off = 1; off < 512; off <<= 1) {
        int add = (t >= off) ? s[t - off] : 0;
        __syncthreads();
        s[t] += add;
        __syncthreads();
    }
    if (t < nb) p[t] = s[t] - v;            // exclusive
}

__global__ void scan3_kernel(int* __restrict__ row_start, const int* __restrict__ partials,
                             int* __restrict__ cursor, int n, int total) {
    int i = blockIdx.x * 256 + threadIdx.x;
    if (i < n) {
        int v = row_start[i] + partials[blockIdx.x];
        row_start[i] = v;
        cursor[i] = v;
    }
    if (i == 0) row_start[n] = total;
}

// ---------------------------------------------------------------- CSR fill
__global__ void csr_fill_kernel(const int* __restrict__ rows, const int* __restrict__ cols,
                                int* __restrict__ cursor, int* __restrict__ csr_col) {
    int e = blockIdx.x * 256 + threadIdx.x;
    if (e < N_EDGES) {
        int pos = atomicAdd(&cursor[rows[e]], 1);
        csr_col[pos] = cols[e];
    }
}

// ---------------------------------------------------------------- pre-scale: buf0 = dinv * x
__global__ void prescale_kernel(const float4* __restrict__ x, const float* __restrict__ dinv,
                                float4* __restrict__ out) {
    int i = blockIdx.x * 256 + threadIdx.x;   // N_NODES * 16 float4
    if (i < N_NODES * (IN_F / 4)) {
        int node = i >> 4;                    // 16 float4 per node
        float d = dinv[node];
        float4 v = x[i];
        v.x *= d; v.y *= d; v.z *= d; v.w *= d;
        out[i] = v;
    }
}

// ---------------------------------------------------------------- one hop: out = scale ⊙ (A+I) in
// wave (64 lanes) per node, lane = feature. squared: scale = dinv^2 (intermediate) else dinv (final).
__global__ void hop_kernel(const float* __restrict__ in, float* __restrict__ out,
                           const int* __restrict__ row_start, const int* __restrict__ csr_col,
                           const float* __restrict__ dinv, int squared) {
    int node = blockIdx.x * 4 + (threadIdx.x >> 6);
    int lane = threadIdx.x & 63;
    if (node >= N_NODES) return;
    int beg = row_start[node];
    int end = row_start[node + 1];
    float acc = in[node * IN_F + lane];       // self loop (I term)
    for (int base = beg; base < end; base += 64) {
        int idx = base + lane;
        int cv = (idx < end) ? csr_col[idx] : 0;
        int cnt = min(64, end - base);
        #pragma unroll 4
        for (int j = 0; j < cnt; ++j) {
            int c = __shfl(cv, j);
            acc += in[c * IN_F + lane];
        }
    }
    float d = dinv[node];
    float s = squared ? d * d : d;
    out[node * IN_F + lane] = acc * s;
}

// ---------------------------------------------------------------- cluster accumulate
__global__ void cluster_acc_kernel(const float* __restrict__ x3, const int* __restrict__ cl,
                                   float* __restrict__ xc, int* __restrict__ ccnt) {
    int node = blockIdx.x * 4 + (threadIdx.x >> 6);
    int lane = threadIdx.x & 63;
    if (node >= N_NODES) return;
    int c = cl[node];
    if (lane == 0) atomicAdd(&ccnt[c], 1);
    atomicAdd(&xc[c * IN_F + lane], x3[node * IN_F + lane]);
}

// ---------------------------------------------------------------- cluster GEMM: h = (xc/cnt) @ W^T + b
__global__ void cluster_gemm_kernel(const float* __restrict__ xc, const int* __restrict__ ccnt,
                                    const float* __restrict__ W, const float* __restrict__ b,
                                    float* __restrict__ h) {
    __shared__ float Ws[OUT_F * 65];          // pad 64->65: bank = (o + k) % 32, conflict-free-ish
    for (int i = threadIdx.x; i < OUT_F * IN_F; i += 256) {
        Ws[(i >> 6) * 65 + (i & 63)] = W[i];
    }
    __syncthreads();
    int idx = blockIdx.x * 256 + threadIdx.x;
    if (idx >= N_CLUSTERS * OUT_F) return;
    int c = idx / OUT_F;
    int o = idx - c * OUT_F;
    float inv = 1.0f / fmaxf((float)ccnt[c], 1.0f);
    const float* xr = xc + c * IN_F;
    const float* wr = Ws + o * 65;
    float acc = 0.0f;
    #pragma unroll
    for (int k = 0; k < IN_F; ++k) acc += xr[k] * wr[k];
    h[idx] = acc * inv + b[o];
}

// ---------------------------------------------------------------- gather back: out[i] = h[cluster[i]]
__global__ void scatter_out_kernel(const float4* __restrict__ h, const int* __restrict__ cl,
                                   float4* __restrict__ out) {
    int i = blockIdx.x * 256 + threadIdx.x;   // N_NODES * 10 float4
    if (i < N_NODES * (OUT_F / 4)) {
        int node = i / 10;
        int q = i - node * 10;
        out[i] = h[cl[node] * 10 + q];
    }
}

// ---------------------------------------------------------------- launch
extern "C" void kernel_launch(void* const* d_in, const int* in_sizes, int n_in,
                              void* d_out, int out_size, void* d_ws, size_t ws_size,
                              hipStream_t stream) {
    const float* x    = (const float*)d_in[0];
    const int*   rows = (const int*)d_in[1];                 // edge_index[0] = targets
    const int*   cols = (const int*)d_in[1] + N_EDGES;       // edge_index[1] = sources
    const int*   cl   = (const int*)d_in[2];
    const float* W    = (const float*)d_in[4];
    const float* b    = (const float*)d_in[5];
    float* out = (float*)d_out;

    // workspace layout (all offsets in 4-byte elems, 16B aligned)
    size_t off = 0;
    auto alloc = [&](size_t elems) -> void* {
        void* p = (char*)d_ws + off * 4;
        off += (elems + 3) & ~(size_t)3;
        return p;
    };
    // zeroed region first (single memset): deg_cnt | ccnt | xc_sum
    int*   deg_cnt = (int*)alloc(N_NODES);
    int*   ccnt    = (int*)alloc(N_CLUSTERS);
    float* xc_sum  = (float*)alloc((size_t)N_CLUSTERS * IN_F);
    size_t zero_elems = off;
    float* dinv      = (float*)alloc(N_NODES);
    int*   row_start = (int*)alloc(N_NODES + 1);
    int*   cursor    = (int*)alloc(N_NODES);
    int*   csr_col   = (int*)alloc(N_EDGES);
    int*   partials  = (int*)alloc(512);
    float* buf0      = (float*)alloc((size_t)N_NODES * IN_F);
    float* buf1      = (float*)alloc((size_t)N_NODES * IN_F);
    float* h         = (float*)alloc((size_t)N_CLUSTERS * OUT_F);
    (void)ws_size; (void)in_sizes; (void)n_in; (void)out_size;

    hipMemsetAsync(d_ws, 0, zero_elems * 4, stream);

    const int EB = (N_EDGES + 255) / 256;     // 6250
    const int NB = (N_NODES + 255) / 256;     // 391
    const int WB = N_NODES / 4;               // 25000 (one wave per node, 4 nodes/block)

    deg_count_kernel<<<EB, 256, 0, stream>>>(rows, deg_cnt);
    dinv_kernel<<<NB, 256, 0, stream>>>(deg_cnt, dinv);
    scan1_kernel<<<NB, 256, 0, stream>>>(deg_cnt, row_start, partials, N_NODES);
    scan2_kernel<<<1, 512, 0, stream>>>(partials, NB);
    scan3_kernel<<<NB, 256, 0, stream>>>(row_start, partials, cursor, N_NODES, N_EDGES);
    csr_fill_kernel<<<EB, 256, 0, stream>>>(rows, cols, cursor, csr_col);

    prescale_kernel<<<(N_NODES * 16 + 255) / 256, 256, 0, stream>>>((const float4*)x, dinv, (float4*)buf0);

    hop_kernel<<<WB, 256, 0, stream>>>(buf0, buf1, row_start, csr_col, dinv, 1);
    hop_kernel<<<WB, 256, 0, stream>>>(buf1, buf0, row_start, csr_col, dinv, 1);
    hop_kernel<<<WB, 256, 0, stream>>>(buf0, buf1, row_start, csr_col, dinv, 0);

    cluster_acc_kernel<<<WB, 256, 0, stream>>>(buf1, cl, xc_sum, ccnt);
    cluster_gemm_kernel<<<(N_CLUSTERS * OUT_F + 255) / 256, 256, 0, stream>>>(xc_sum, ccnt, W, b, h);
    scatter_out_kernel<<<(N_NODES * 10 + 255) / 256, 256, 0, stream>>>((const float4*)h, cl, (float4*)out);
}

// Round 2
// 490.534 us; speedup vs baseline: 1.3233x; 1.3233x over previous
//
#include <hip/hip_runtime.h>

#define N_NODES    100000
#define N_EDGES    1600000
#define IN_F       64
#define OUT_F      40
#define N_CLUSTERS 10000

#define BUCK_SHIFT 9                                  // 512 rows per bucket
#define NBUCK      ((N_NODES + 511) >> BUCK_SHIFT)    // 196
#define TILE_E     4096
#define EPT        (TILE_E / 256)                     // 16 edges per thread
#define FILL_SPLIT 8

// ---------------------------------------------------------------- bucket histogram
__global__ void bucket_hist_kernel(const int* __restrict__ rows, int* __restrict__ bhist) {
    __shared__ int lh[NBUCK];
    int t = threadIdx.x;
    for (int i = t; i < NBUCK; i += 256) lh[i] = 0;
    __syncthreads();
    int e0 = blockIdx.x * TILE_E;
    #pragma unroll
    for (int k = 0; k < EPT; ++k) {
        int e = e0 + t + k * 256;
        if (e < N_EDGES) atomicAdd(&lh[rows[e] >> BUCK_SHIFT], 1);
    }
    __syncthreads();
    for (int i = t; i < NBUCK; i += 256) {
        int c = lh[i];
        if (c) atomicAdd(&bhist[i], c);
    }
}

// ---------------------------------------------------------------- bucket scan (exclusive)
__global__ void bucket_scan_kernel(const int* __restrict__ bhist, int* __restrict__ bbase,
                                   int* __restrict__ bcursor) {
    __shared__ int s[256];
    int t = threadIdx.x;
    int v = (t < NBUCK) ? bhist[t] : 0;
    s[t] = v;
    __syncthreads();
    for (int off = 1; off < 256; off <<= 1) {
        int a = (t >= off) ? s[t - off] : 0;
        __syncthreads();
        s[t] += a;
        __syncthreads();
    }
    if (t < NBUCK) { int ex = s[t] - v; bbase[t] = ex; bcursor[t] = ex; }
    if (t == 0) bbase[NBUCK] = N_EDGES;
}

// ---------------------------------------------------------------- bin scatter (LDS-ordered, coalesced out)
__global__ void bin_scatter_kernel(const int* __restrict__ rows, const int* __restrict__ cols,
                                   int* __restrict__ bcursor, uint2* __restrict__ bins) {
    __shared__ uint2 se[TILE_E];          // 32 KB staging, ordered by bucket
    __shared__ int lh[NBUCK];             // per-block bucket counts
    __shared__ int lsc[NBUCK];            // exclusive scan of lh
    __shared__ int lb[NBUCK];             // global base per bucket for this block
    __shared__ int sc[256];
    int t = threadIdx.x;
    for (int i = t; i < NBUCK; i += 256) lh[i] = 0;
    __syncthreads();
    int e0 = blockIdx.x * TILE_E;
    int r[EPT], c[EPT], rk[EPT];
    #pragma unroll
    for (int k = 0; k < EPT; ++k) {
        int e = e0 + t + k * 256;
        if (e < N_EDGES) {
            r[k] = rows[e]; c[k] = cols[e];
            rk[k] = atomicAdd(&lh[r[k] >> BUCK_SHIFT], 1);
        } else r[k] = -1;
    }
    __syncthreads();
    // exclusive scan lh -> lsc ; reserve global space -> lb
    int v = (t < NBUCK) ? lh[t] : 0;
    sc[t] = v;
    __syncthreads();
    for (int off = 1; off < 256; off <<= 1) {
        int a = (t >= off) ? sc[t - off] : 0;
        __syncthreads();
        sc[t] += a;
        __syncthreads();
    }
    if (t < NBUCK) {
        lsc[t] = sc[t] - v;
        lb[t] = v ? atomicAdd(&bcursor[t], v) : 0;
    }
    __syncthreads();
    // place into LDS ordered by bucket
    #pragma unroll
    for (int k = 0; k < EPT; ++k) {
        if (r[k] >= 0) {
            int bu = r[k] >> BUCK_SHIFT;
            se[lsc[bu] + rk[k]] = make_uint2((unsigned)r[k], (unsigned)c[k]);
        }
    }
    __syncthreads();
    // coalesced flush: consecutive idx -> mostly-consecutive global addresses
    #pragma unroll
    for (int k = 0; k < EPT; ++k) {
        int idx = k * 256 + t;
        if (e0 + idx < N_EDGES) {
            uint2 u = se[idx];
            int bu = (int)(u.x >> BUCK_SHIFT);
            bins[lb[bu] + (idx - lsc[bu])] = u;
        }
    }
}

// ---------------------------------------------------------------- degree from binned edges (L2-local atomics)
__global__ void deg_from_bins_kernel(const uint2* __restrict__ bins, int* __restrict__ deg) {
    int i = blockIdx.x * 256 + threadIdx.x;
    if (i < N_EDGES) atomicAdd(&deg[bins[i].x], 1);
}

// deg includes self-loop (+1); dinv = rsqrt(deg)
__global__ void dinv_kernel(const int* __restrict__ deg, float* __restrict__ dinv) {
    int i = blockIdx.x * 256 + threadIdx.x;
    if (i < N_NODES) dinv[i] = rsqrtf((float)(deg[i] + 1));
}

// ---------------------------------------------------------------- node scan (exclusive)
__global__ void scan1_kernel(const int* __restrict__ in, int* __restrict__ out,
                             int* __restrict__ partials, int n) {
    __shared__ int s[256];
    int t = threadIdx.x;
    int i = blockIdx.x * 256 + t;
    int v = (i < n) ? in[i] : 0;
    s[t] = v;
    __syncthreads();
    for (int off = 1; off < 256; off <<= 1) {
        int add = (t >= off) ? s[t - off] : 0;
        __syncthreads();
        s[t] += add;
        __syncthreads();
    }
    if (i < n) out[i] = s[t] - v;           // exclusive
    if (t == 255) partials[blockIdx.x] = s[255];
}

__global__ void scan2_kernel(int* __restrict__ p, int nb) {
    __shared__ int s[512];
    int t = threadIdx.x;
    int v = (t < nb) ? p[t] : 0;
    s[t] = v;
    __syncthreads();
    for (int off = 1; off < 512; off <<= 1) {
        int add = (t >= off) ? s[t - off] : 0;
        __syncthreads();
        s[t] += add;
        __syncthreads();
    }
    if (t < nb) p[t] = s[t] - v;            // exclusive
}

__global__ void scan3_kernel(int* __restrict__ row_start, const int* __restrict__ partials,
                             int* __restrict__ cursor, int n, int total) {
    int i = blockIdx.x * 256 + threadIdx.x;
    if (i < n) {
        int v = row_start[i] + partials[blockIdx.x];
        row_start[i] = v;
        cursor[i] = v;
    }
    if (i == 0) row_start[n] = total;
}

// ---------------------------------------------------------------- CSR fill from bins (L2-local window)
__global__ void bin_fill_kernel(const uint2* __restrict__ bins, const int* __restrict__ bbase,
                                int* __restrict__ cursor, int* __restrict__ csr_col) {
    int b = blockIdx.x / FILL_SPLIT;
    int s = blockIdx.x % FILL_SPLIT;
    int lo = bbase[b], hi = bbase[b + 1];
    int n = hi - lo;
    int chunk = (n + FILL_SPLIT - 1) / FILL_SPLIT;
    int beg = lo + s * chunk;
    int end = min(lo + (s + 1) * chunk, hi);
    for (int i = beg + threadIdx.x; i < end; i += 256) {
        uint2 u = bins[i];
        int pos = atomicAdd(&cursor[u.x], 1);
        csr_col[pos] = (int)u.y;
    }
}

// ---------------------------------------------------------------- pre-scale: buf0 = dinv * x
__global__ void prescale_kernel(const float4* __restrict__ x, const float* __restrict__ dinv,
                                float4* __restrict__ out) {
    int i = blockIdx.x * 256 + threadIdx.x;   // N_NODES * 16 float4
    if (i < N_NODES * (IN_F / 4)) {
        int node = i >> 4;
        float d = dinv[node];
        float4 v = x[i];
        v.x *= d; v.y *= d; v.z *= d; v.w *= d;
        out[i] = v;
    }
}

// ---------------------------------------------------------------- one hop: out = scale ⊙ (A+I) in
// wave per node; lane = (neighbor slot 0..3) x (feature quad 0..15), float4 loads.
__global__ void hop_kernel(const float* __restrict__ in, float* __restrict__ out,
                           const int* __restrict__ row_start, const int* __restrict__ csr_col,
                           const float* __restrict__ dinv, int squared) {
    int node = (blockIdx.x * 256 + threadIdx.x) >> 6;
    int lane = threadIdx.x & 63;
    if (node >= N_NODES) return;
    int beg = row_start[node];
    int end = row_start[node + 1];
    int sub = lane >> 4;        // which of 4 neighbor slots
    int q   = lane & 15;        // feature quad
    const float4* in4 = (const float4*)in;
    float4 acc = (sub == 0) ? in4[node * 16 + q] : make_float4(0.f, 0.f, 0.f, 0.f);
    for (int base = beg; base < end; base += 64) {
        int idx = base + lane;
        int cv = (idx < end) ? csr_col[idx] : 0;
        int nIter = min(64, end - base);
        for (int j = 0; j < nIter; j += 4) {
            int my = j + sub;
            int c = __shfl(cv, my);
            if (base + my < end) {
                float4 v = in4[c * 16 + q];
                acc.x += v.x; acc.y += v.y; acc.z += v.z; acc.w += v.w;
            }
        }
    }
    // reduce the 4 neighbor slots (lanes xor 16, 32)
    acc.x += __shfl_xor(acc.x, 16); acc.y += __shfl_xor(acc.y, 16);
    acc.z += __shfl_xor(acc.z, 16); acc.w += __shfl_xor(acc.w, 16);
    acc.x += __shfl_xor(acc.x, 32); acc.y += __shfl_xor(acc.y, 32);
    acc.z += __shfl_xor(acc.z, 32); acc.w += __shfl_xor(acc.w, 32);
    if (sub == 0) {
        float d = dinv[node];
        float s = squared ? d * d : d;
        acc.x *= s; acc.y *= s; acc.z *= s; acc.w *= s;
        ((float4*)out)[node * 16 + q] = acc;
    }
}

// ---------------------------------------------------------------- cluster accumulate
__global__ void cluster_acc_kernel(const float* __restrict__ x3, const int* __restrict__ cl,
                                   float* __restrict__ xc, int* __restrict__ ccnt) {
    int node = blockIdx.x * 4 + (threadIdx.x >> 6);
    int lane = threadIdx.x & 63;
    if (node >= N_NODES) return;
    int c = cl[node];
    if (lane == 0) atomicAdd(&ccnt[c], 1);
    atomicAdd(&xc[c * IN_F + lane], x3[node * IN_F + lane]);
}

// ---------------------------------------------------------------- cluster GEMM: h = (xc/cnt) @ W^T + b
__global__ void cluster_gemm_kernel(const float* __restrict__ xc, const int* __restrict__ ccnt,
                                    const float* __restrict__ W, const float* __restrict__ b,
                                    float* __restrict__ h) {
    __shared__ float Ws[OUT_F * 65];
    for (int i = threadIdx.x; i < OUT_F * IN_F; i += 256) {
        Ws[(i >> 6) * 65 + (i & 63)] = W[i];
    }
    __syncthreads();
    int idx = blockIdx.x * 256 + threadIdx.x;
    if (idx >= N_CLUSTERS * OUT_F) return;
    int c = idx / OUT_F;
    int o = idx - c * OUT_F;
    float inv = 1.0f / fmaxf((float)ccnt[c], 1.0f);
    const float* xr = xc + c * IN_F;
    const float* wr = Ws + o * 65;
    float acc = 0.0f;
    #pragma unroll
    for (int k = 0; k < IN_F; ++k) acc += xr[k] * wr[k];
    h[idx] = acc * inv + b[o];
}

// ---------------------------------------------------------------- gather back: out[i] = h[cluster[i]]
__global__ void scatter_out_kernel(const float4* __restrict__ h, const int* __restrict__ cl,
                                   float4* __restrict__ out) {
    int i = blockIdx.x * 256 + threadIdx.x;   // N_NODES * 10 float4
    if (i < N_NODES * (OUT_F / 4)) {
        int node = i / 10;
        int q = i - node * 10;
        out[i] = h[cl[node] * 10 + q];
    }
}

// ---------------------------------------------------------------- launch
extern "C" void kernel_launch(void* const* d_in, const int* in_sizes, int n_in,
                              void* d_out, int out_size, void* d_ws, size_t ws_size,
                              hipStream_t stream) {
    const float* x    = (const float*)d_in[0];
    const int*   rows = (const int*)d_in[1];                 // edge_index[0] = targets
    const int*   cols = (const int*)d_in[1] + N_EDGES;       // edge_index[1] = sources
    const int*   cl   = (const int*)d_in[2];
    const float* W    = (const float*)d_in[4];
    const float* b    = (const float*)d_in[5];
    float* out = (float*)d_out;

    size_t off = 0;
    auto alloc = [&](size_t elems) -> void* {
        void* p = (char*)d_ws + off * 4;
        off += (elems + 3) & ~(size_t)3;
        return p;
    };
    // zeroed region first (single memset): deg_cnt | ccnt | xc_sum | bhist
    int*   deg_cnt = (int*)alloc(N_NODES);
    int*   ccnt    = (int*)alloc(N_CLUSTERS);
    float* xc_sum  = (float*)alloc((size_t)N_CLUSTERS * IN_F);
    int*   bhist   = (int*)alloc(NBUCK);
    size_t zero_elems = off;
    float* dinv      = (float*)alloc(N_NODES);
    int*   row_start = (int*)alloc(N_NODES + 1);
    int*   cursor    = (int*)alloc(N_NODES);
    int*   csr_col   = (int*)alloc(N_EDGES);
    int*   bbase     = (int*)alloc(NBUCK + 1);
    int*   bcursor   = (int*)alloc(NBUCK);
    int*   partials  = (int*)alloc(512);
    float* buf0      = (float*)alloc((size_t)N_NODES * IN_F);
    float* buf1      = (float*)alloc((size_t)N_NODES * IN_F);
    float* h         = (float*)alloc((size_t)N_CLUSTERS * OUT_F);
    uint2* bins      = (uint2*)buf1;   // 12.8 MB, dead before hop1 writes buf1
    (void)ws_size; (void)in_sizes; (void)n_in; (void)out_size;

    hipMemsetAsync(d_ws, 0, zero_elems * 4, stream);

    const int TB = (N_EDGES + TILE_E - 1) / TILE_E;   // 391
    const int EB = (N_EDGES + 255) / 256;             // 6250
    const int NB = (N_NODES + 255) / 256;             // 391
    const int WB = N_NODES / 4;                       // 25000 (wave per node)

    bucket_hist_kernel<<<TB, 256, 0, stream>>>(rows, bhist);
    bucket_scan_kernel<<<1, 256, 0, stream>>>(bhist, bbase, bcursor);
    bin_scatter_kernel<<<TB, 256, 0, stream>>>(rows, cols, bcursor, bins);
    deg_from_bins_kernel<<<EB, 256, 0, stream>>>(bins, deg_cnt);
    dinv_kernel<<<NB, 256, 0, stream>>>(deg_cnt, dinv);
    scan1_kernel<<<NB, 256, 0, stream>>>(deg_cnt, row_start, partials, N_NODES);
    scan2_kernel<<<1, 512, 0, stream>>>(partials, NB);
    scan3_kernel<<<NB, 256, 0, stream>>>(row_start, partials, cursor, N_NODES, N_EDGES);
    bin_fill_kernel<<<NBUCK * FILL_SPLIT, 256, 0, stream>>>(bins, bbase, cursor, csr_col);

    prescale_kernel<<<(N_NODES * 16 + 255) / 256, 256, 0, stream>>>((const float4*)x, dinv, (float4*)buf0);

    hop_kernel<<<WB, 256, 0, stream>>>(buf0, buf1, row_start, csr_col, dinv, 1);
    hop_kernel<<<WB, 256, 0, stream>>>(buf1, buf0, row_start, csr_col, dinv, 1);
    hop_kernel<<<WB, 256, 0, stream>>>(buf0, buf1, row_start, csr_col, dinv, 0);

    cluster_acc_kernel<<<WB, 256, 0, stream>>>(buf1, cl, xc_sum, ccnt);
    cluster_gemm_kernel<<<(N_CLUSTERS * OUT_F + 255) / 256, 256, 0, stream>>>(xc_sum, ccnt, W, b, h);
    scatter_out_kernel<<<(N_NODES * 10 + 255) / 256, 256, 0, stream>>>((const float4*)h, cl, (float4*)out);
}